// Round 1
// baseline (127.858 us; speedup 1.0000x reference)
//
#include <hip/hip_runtime.h>
#include <math.h>

// PointLaplacianLoss — grid-pruned exact KNN, round 11.
//
// Round-10 lesson: bounds are batched, but each of the 9 (or 25) runs still
// *starts* with a dependent prime load -> ~10 (or ~26) serialized L2
// round-trips per wave.  This round:
//   * prime-load batching: the first candidate of each run is loaded in
//     predicated chunks of 5 independent loads BEFORE the gather loop —
//     S=1 collapses to ~3 round-trips, S=2 to ~7.  CH=5 keeps the VGPR
//     count under the 128-reg cap forced by __launch_bounds__(1024).
//   * wave-uniform sCov: if ANY lane is sparse (q2>4.8) the whole wave runs
//     only the 5^3 path (superset of 3^3).  Mixed waves previously paid
//     T1+T2 exec-masked serially; now T2 only, and promoted lanes gain
//     coverage R=2H+df -> fewer phase-2 failures.
//   * scan_cells histogram loads vectorized to int4 (minor).
// Build pipeline, merge, phase2 otherwise unchanged from round 10.

constexpr int NPTS  = 8192;
constexpr int NB    = 2;
constexpr int KNN   = 10;
constexpr int QPB   = 64;
constexpr int WPB   = 16;               // wave-slices per query
constexpr int BLOCK = QPB * WPB;        // 1024
constexpr int MASK13 = 0xFFFFE000;

constexpr int   G    = 32;
constexpr int   NC   = G * G * G;
constexpr float BMIN = -5.5f;
constexpr float BW   = 11.0f;
constexpr float H    = BW / G;          // 0.34375
constexpr float INVH = (float)G / BW;

// ---------------- selection helpers ----------------
__device__ __forceinline__ void ins1(int l[KNN], int x) {
#pragma unroll
    for (int k = KNN - 1; k > 0; --k) l[k] = min(l[k], max(l[k - 1], x));
    l[0] = min(l[0], x);
}
__device__ __forceinline__ void ins2(int l[KNN], int a, int b) {
    const int b0 = min(a, b), b1 = max(a, b);
#pragma unroll
    for (int k = KNN - 1; k >= 2; --k)
        l[k] = min(l[k], min(max(l[k - 1], b0), max(l[k - 2], b1)));
    l[1] = min(l[1], min(max(l[0], b0), b1));
    l[0] = min(l[0], b0);
}
template<int S>
__device__ __forceinline__ void ins2s(int l[KNN], int a, int b) {
    const int b0 = min(a, b), b1 = max(a, b);
#pragma unroll
    for (int k = KNN - 1; k >= S + 2; --k)
        l[k] = min(l[k], min(max(l[k - 1], b0), max(l[k - 2], b1)));
    l[S + 1] = min(l[S + 1], min(max(l[S], b0), b1));
    l[S] = min(l[S], b0);
}
__device__ __forceinline__ void merge_sorted(int l[KNN], const int p[KNN]) {
    ins2s<0>(l, p[0], p[1]);
    ins2s<2>(l, p[2], p[3]);
    ins2s<4>(l, p[4], p[5]);
    ins2s<6>(l, p[6], p[7]);
    ins2s<8>(l, p[8], p[9]);
}

// ---------------- build kernels ----------------
__global__ void pack_bin(const float* __restrict__ p1, float4* __restrict__ w,
                         int* __restrict__ hist, int* __restrict__ cellof,
                         float* __restrict__ out, int* __restrict__ nfail) {
    const int i = blockIdx.x * blockDim.x + threadIdx.x;
    if (i >= NB * NPTS) return;
    if (i == 0) { out[0] = 0.0f; nfail[0] = 0; }
    const float x = p1[3 * i], y = p1[3 * i + 1], z = p1[3 * i + 2];
    w[i] = make_float4(x, y, z, fmaf(x, x, fmaf(y, y, z * z)));
    const int cx = min(max((int)floorf((x - BMIN) * INVH), 0), G - 1);
    const int cy = min(max((int)floorf((y - BMIN) * INVH), 0), G - 1);
    const int cz = min(max((int)floorf((z - BMIN) * INVH), 0), G - 1);
    const int c = (cz << 10) | (cy << 5) | cx;
    cellof[i] = c;
    atomicAdd(&hist[(i >> 13) * NC + c], 1);
}

__global__ __launch_bounds__(1024)
void scan_cells(const int* __restrict__ hist, int* __restrict__ starts) {
    __shared__ int wsum[16];
    const int b = blockIdx.x, t = threadIdx.x;
    const int* hb = hist + b * NC;
    int* sb = starts + b * (NC + 1);
    const int c0 = t * 32;
    const int4* hb4 = (const int4*)(hb + c0);   // hist 16B-aligned, c0*4 % 16 == 0
    int loc[32]; int sum = 0;
#pragma unroll
    for (int j = 0; j < 8; ++j) {
        const int4 v = hb4[j];
        loc[4 * j + 0] = v.x; loc[4 * j + 1] = v.y;
        loc[4 * j + 2] = v.z; loc[4 * j + 3] = v.w;
        sum += v.x + v.y + v.z + v.w;
    }
    const int lane = t & 63, wvi = t >> 6;
    int incl = sum;
#pragma unroll
    for (int off = 1; off < 64; off <<= 1) {
        const int v = __shfl_up(incl, off);
        if (lane >= off) incl += v;
    }
    if (lane == 63) wsum[wvi] = incl;
    __syncthreads();
    if (t < 16) {
        const int v = wsum[t];
        int iv = v;
#pragma unroll
        for (int off = 1; off < 16; off <<= 1) {
            const int u = __shfl_up(iv, off);
            if (t >= off) iv += u;
        }
        wsum[t] = iv - v;
    }
    __syncthreads();
    int run = wsum[wvi] + incl - sum;
#pragma unroll
    for (int j = 0; j < 32; ++j) { sb[c0 + j] = run; run += loc[j]; }
    if (t == 1023) sb[NC] = run;
}

__global__ void scatter_all(const int* __restrict__ cellof,
                            const int* __restrict__ starts,
                            int* __restrict__ hist,
                            const float4* __restrict__ w,
                            const float* __restrict__ p2,
                            float4* __restrict__ wsorted,
                            float4* __restrict__ p2s) {
    const int i = blockIdx.x * blockDim.x + threadIdx.x;
    if (i >= NB * NPTS) return;
    const int b = i >> 13;
    const int c = cellof[i];
    const int old = atomicSub(&hist[b * NC + c], 1);
    const int pos = b * NPTS + starts[b * (NC + 1) + c] + old - 1;
    wsorted[pos] = w[i];
    p2s[pos] = make_float4(p2[3 * i], p2[3 * i + 1], p2[3 * i + 2], 0.0f);
}

// ---------------- phase 1: prime-batched adaptive scan ----------------
// Bounds loaded up-front (round 10) AND the first candidate of every run
// prime-loaded in predicated chunks of CH=5 independent loads, so the per-run
// dependent L2 round-trips collapse: S=1 ~10 -> ~3 trips, S=2 ~26 -> ~7.
template<int S>
__device__ __forceinline__ void scan_batched(const float4* __restrict__ W,
                                             const int* __restrict__ st,
                                             int cx, int cy, int cz,
                                             float m2x, float m2y, float m2z,
                                             float q2, int qpos, int wv,
                                             int l[KNN])
{
    constexpr int Wd = 2 * S + 1;
    constexpr int R  = Wd * Wd;
    constexpr int CH = 5;               // prime-chunk width (VGPR budget: +20)
    const int IMAX = 0x7FFFFFFF;
    int J0[R], J1[R];
#pragma unroll
    for (int r = 0; r < R; ++r) {
        const int dy = r % Wd - S, dz = r / Wd - S;   // compile-time
        const int ay = cy + dy, az = cz + dz;
        const bool ok = ((unsigned)ay < G) && ((unsigned)az < G);
        const int cbase = (az << 10) | (ay << 5);
        const int lo = cbase + max(cx - S, 0);
        const int hi = cbase + min(cx + S, G - 1) + 1;
        J0[r] = ok ? st[lo] : 0;                      // predicated, independent
        J1[r] = ok ? st[hi] : 0;
    }
#pragma unroll
    for (int base = 0; base < R; base += CH) {
        float4 P[CH];
#pragma unroll
        for (int c = 0; c < CH; ++c) {
            const int r = base + c;                   // compile-time
            if (r < R) {
                // clamped address: harmless garbage load for empty runs,
                // stays inside this batch's slice; all CH loads independent.
                const int j = min(J0[r] + wv, NPTS - 1);
                P[c] = W[j];
            }
        }
#pragma unroll
        for (int c = 0; c < CH; ++c) {
            const int r = base + c;
            if (r < R) {
                const int j1 = J1[r];
                int j = J0[r] + wv;
                if (j < j1) {
                    float4 c4 = P[c];                 // primed, already in flight
                    while (true) {
                        const int jn = j + WPB;
                        const bool more = jn < j1;
                        float4 nx;
                        if (more) nx = W[jn];         // prefetch next
                        const float d2 = fmaf(m2x, c4.x,
                                         fmaf(m2y, c4.y,
                                         fmaf(m2z, c4.z, c4.w + q2)));
                        int key = (__float_as_int(d2) & MASK13) | j;
                        key = (j == qpos) ? IMAX : key;
                        ins1(l, key);
                        if (!more) break;
                        c4 = nx; j = jn;
                    }
                }
            }
        }
    }
}

__global__ __launch_bounds__(BLOCK)
void phase1(const float4* __restrict__ wsorted, const float4* __restrict__ p2s,
            const int* __restrict__ starts, float* __restrict__ out,
            int* __restrict__ nfail, int* __restrict__ worklist)
{
    __shared__ int mv[WPB * KNN * QPB];      // 40 KB

    const int batch = blockIdx.x >> 7;
    const int lane  = threadIdx.x & 63;
    const int wv    = __builtin_amdgcn_readfirstlane(threadIdx.x >> 6);
    const int qpos  = ((blockIdx.x & 127) << 6) + lane;

    const float4* W  = wsorted + batch * NPTS;
    const float4* P2 = p2s + batch * NPTS;
    const int*    st = starts + batch * (NC + 1);

    const float4 qp = W[qpos];
    const int cx = min(max((int)floorf((qp.x - BMIN) * INVH), 0), G - 1);
    const int cy = min(max((int)floorf((qp.y - BMIN) * INVH), 0), G - 1);
    const int cz = min(max((int)floorf((qp.z - BMIN) * INVH), 0), G - 1);
    const float lox = BMIN + cx * H, loy = BMIN + cy * H, loz = BMIN + cz * H;
    const float df = fminf(fminf(fminf(qp.x - lox, lox + H - qp.x),
                                 fminf(qp.y - loy, loy + H - qp.y)),
                           fminf(qp.z - loz, loz + H - qp.z));
    const float m2x = -2.0f * qp.x, m2y = -2.0f * qp.y, m2z = -2.0f * qp.z;
    const float q2 = qp.w;
    const int IMAX = 0x7FFFFFFF;

    // wave-uniform reach: if ANY lane is sparse, the whole wave takes the 5^3
    // path (superset of 3^3) -- mixed waves previously ran BOTH paths serially
    // under complementary exec masks.  Identical across the 16 wave-slices of
    // a query block (same lane -> same query), so merge/coverage stay
    // consistent.
    const bool wide = __any(q2 > 4.8f);
    const int sCov = wide ? 2 : 1;

    int l[KNN];
#pragma unroll
    for (int k = 0; k < KNN; ++k) l[k] = IMAX;

    if (!wide)
        scan_batched<1>(W, st, cx, cy, cz, m2x, m2y, m2z, q2, qpos, wv, l);
    else
        scan_batched<2>(W, st, cx, cy, cz, m2x, m2y, m2z, q2, qpos, wv, l);

#pragma unroll
    for (int k = 0; k < KNN; ++k) mv[(wv * KNN + k) * QPB + lane] = l[k];
    __syncthreads();

    if (threadIdx.x < QPB) {
        int M[KNN];
#pragma unroll
        for (int k = 0; k < KNN; ++k) M[k] = IMAX;
#pragma unroll
        for (int e = 0; e < WPB; ++e) {
            int p[KNN];
#pragma unroll
            for (int k = 0; k < KNN; ++k) p[k] = mv[(e * KNN + k) * QPB + lane];
            merge_sorted(M, p);
        }

        const float tau = __int_as_float(M[KNN - 1] & MASK13);
        const float R = (float)sCov * H + df;         // wave-uniform coverage
        const bool covered = (tau <= R * R * 0.996f); // truncation margin
        float v = 0.0f;
        if (covered) {
            float s1x = 0, s1y = 0, s1z = 0, s2x = 0, s2y = 0, s2z = 0;
#pragma unroll
            for (int k = 0; k < KNN; ++k) {
                const int j = M[k] & (NPTS - 1);
                const float4 c4 = W[j];
                const float4 n2 = P2[j];
                s1x += c4.x; s1y += c4.y; s1z += c4.z;
                s2x += n2.x; s2y += n2.y; s2z += n2.z;
            }
            const float4 p2v = P2[qpos];
            const float dx = (s1x * 0.1f - qp.x) - (s2x * 0.1f - p2v.x);
            const float dy2 = (s1y * 0.1f - qp.y) - (s2y * 0.1f - p2v.y);
            const float dz2 = (s1z * 0.1f - qp.z) - (s2z * 0.1f - p2v.z);
            v = fabsf(dx) + fabsf(dy2) + fabsf(dz2);
        } else {
            const int wi = atomicAdd(nfail, 1);
            worklist[wi] = (batch << 16) | qpos;
        }
#pragma unroll
        for (int off = 32; off >= 1; off >>= 1) v += __shfl_down(v, off);
        if (threadIdx.x == 0)
            atomicAdd(out, v * (1.0f / (float)(NB * NPTS * 3)));
    }
}

// ---------------- phase 2: wave-per-query exact brute force ----------------
constexpr int P2BLK = 256;
constexpr int P2GRID = 512;

__global__ __launch_bounds__(P2BLK)
void phase2(const float4* __restrict__ wsorted, const float4* __restrict__ p2s,
            const int* __restrict__ nfail, const int* __restrict__ worklist,
            float* __restrict__ out)
{
    const int lane = threadIdx.x & 63;
    const int wv   = threadIdx.x >> 6;
    const int wid  = blockIdx.x * (P2BLK / 64) + wv;
    const int NW   = P2GRID * (P2BLK / 64);
    const int nf   = *nfail;
    const int IMAX = 0x7FFFFFFF;
    float acc = 0.0f;

    for (int i = wid; i < nf; i += NW) {
        const int e = worklist[i];
        const int batch = e >> 16, qpos = e & 0xFFFF;
        const float4* W  = wsorted + batch * NPTS;
        const float4* P2 = p2s + batch * NPTS;
        const float4 qp = W[qpos];
        const float m2x = -2.0f * qp.x, m2y = -2.0f * qp.y, m2z = -2.0f * qp.z;
        const float q2 = qp.w;

        int l[KNN];
#pragma unroll
        for (int k = 0; k < KNN; ++k) l[k] = IMAX;

#pragma unroll 2
        for (int it = 0; it < NPTS / 128; ++it) {
            const int ja = it * 128 + lane, jb = ja + 64;
            const float4 ca = W[ja];
            const float4 cb = W[jb];
            const float da = fmaf(m2x, ca.x, fmaf(m2y, ca.y, fmaf(m2z, ca.z, ca.w + q2)));
            const float db = fmaf(m2x, cb.x, fmaf(m2y, cb.y, fmaf(m2z, cb.z, cb.w + q2)));
            int ka = (__float_as_int(da) & MASK13) | ja;
            int kb = (__float_as_int(db) & MASK13) | jb;
            ka = (ja == qpos) ? IMAX : ka;
            kb = (jb == qpos) ? IMAX : kb;
            ins2(l, ka, kb);
        }
        for (int off = 1; off < 64; off <<= 1) {
            int p[KNN];
#pragma unroll
            for (int k = 0; k < KNN; ++k) p[k] = __shfl_xor(l[k], off);
            merge_sorted(l, p);
        }
        float s1x = 0, s1y = 0, s1z = 0, s2x = 0, s2y = 0, s2z = 0;
#pragma unroll
        for (int k = 0; k < KNN; ++k) {
            const int j = l[k] & (NPTS - 1);
            const float4 c4 = W[j];
            const float4 n2 = P2[j];
            s1x += c4.x; s1y += c4.y; s1z += c4.z;
            s2x += n2.x; s2y += n2.y; s2z += n2.z;
        }
        const float4 p2v = P2[qpos];
        const float dx = (s1x * 0.1f - qp.x) - (s2x * 0.1f - p2v.x);
        const float dy = (s1y * 0.1f - qp.y) - (s2y * 0.1f - p2v.y);
        const float dz = (s1z * 0.1f - qp.z) - (s2z * 0.1f - p2v.z);
        if (lane == 0) acc += fabsf(dx) + fabsf(dy) + fabsf(dz);
    }

    if (lane == 0 && acc != 0.0f)
        atomicAdd(out, acc * (1.0f / (float)(NB * NPTS * 3)));
}

// ---------------- round-2 fallback (O(N^2), verified) ----------------
constexpr int FB_WPB = 8;
constexpr int FB_BLOCK = QPB * FB_WPB;  // 512
constexpr int CHUNK = NPTS / FB_WPB;

__global__ void prep_pack(const float* __restrict__ p, float4* __restrict__ w) {
    const int i = blockIdx.x * blockDim.x + threadIdx.x;
    if (i < NB * NPTS) {
        const float x = p[3 * i], y = p[3 * i + 1], z = p[3 * i + 2];
        w[i] = make_float4(x, y, z, fmaf(x, x, fmaf(y, y, z * z)));
    }
}

__global__ __launch_bounds__(FB_BLOCK, 2)
void knn_lap(const float4* __restrict__ w1, const float* __restrict__ p2,
             float* __restrict__ out)
{
    __shared__ int mv[FB_WPB * KNN * QPB];
    const int batch = blockIdx.x >> 7;
    const int qbase = (blockIdx.x & 127) << 6;
    const int lane  = threadIdx.x & 63;
    const int wv    = __builtin_amdgcn_readfirstlane(threadIdx.x >> 6);
    const int query = qbase + lane;
    const float4* Wb = w1 + batch * NPTS;
    const float4 qp = Wb[query];
    const float m2x = -2.0f * qp.x, m2y = -2.0f * qp.y, m2z = -2.0f * qp.z;
    const float q2 = qp.w;
    const int IMAX = 0x7FFFFFFF;
    int l[KNN];
#pragma unroll
    for (int k = 0; k < KNN; ++k) l[k] = IMAX;
    const int c0 = wv * CHUNK;
    const float4* cand = Wb + c0;
#pragma unroll 4
    for (int i = 0; i < CHUNK; i += 2) {
        const float4 ca = cand[i];
        const float4 cb = cand[i + 1];
        const int ja = c0 + i, jb = ja + 1;
        const float da = fmaf(m2x, ca.x, fmaf(m2y, ca.y, fmaf(m2z, ca.z, ca.w + q2)));
        const float db = fmaf(m2x, cb.x, fmaf(m2y, cb.y, fmaf(m2z, cb.z, cb.w + q2)));
        int ka = (__float_as_int(da) & MASK13) | ja;
        int kb = (__float_as_int(db) & MASK13) | jb;
        ka = (ja == query) ? IMAX : ka;
        kb = (jb == query) ? IMAX : kb;
        ins2(l, ka, kb);
    }
#pragma unroll
    for (int k = 0; k < KNN; ++k) mv[(wv * KNN + k) * QPB + lane] = l[k];
    __syncthreads();
    if (threadIdx.x < QPB) {
        int m[KNN];
#pragma unroll
        for (int k = 0; k < KNN; ++k) m[k] = IMAX;
#pragma unroll
        for (int e = 0; e < FB_WPB; ++e) {
            int p[KNN];
#pragma unroll
            for (int k = 0; k < KNN; ++k) p[k] = mv[(e * KNN + k) * QPB + lane];
            merge_sorted(m, p);
        }
        const float* P2b = p2 + (size_t)batch * NPTS * 3;
        float s1x = 0, s1y = 0, s1z = 0, s2x = 0, s2y = 0, s2z = 0;
#pragma unroll
        for (int k = 0; k < KNN; ++k) {
            const int j = m[k] & (NPTS - 1);
            const float4 c = Wb[j];
            s1x += c.x; s1y += c.y; s1z += c.z;
            s2x += P2b[3 * j + 0]; s2y += P2b[3 * j + 1]; s2z += P2b[3 * j + 2];
        }
        const int q = qbase + threadIdx.x;
        const float p2x = P2b[3 * q + 0], p2y = P2b[3 * q + 1], p2z = P2b[3 * q + 2];
        const float dx = (s1x * 0.1f - qp.x) - (s2x * 0.1f - p2x);
        const float dy = (s1y * 0.1f - qp.y) - (s2y * 0.1f - p2y);
        const float dz = (s1z * 0.1f - qp.z) - (s2z * 0.1f - p2z);
        float v = fabsf(dx) + fabsf(dy) + fabsf(dz);
#pragma unroll
        for (int off = 32; off >= 1; off >>= 1) v += __shfl_down(v, off);
        if (threadIdx.x == 0)
            atomicAdd(out, v * (1.0f / (float)(NB * NPTS * 3)));
    }
}

// ---------------- launcher ----------------
extern "C" void kernel_launch(void* const* d_in, const int* in_sizes, int n_in,
                              void* d_out, int out_size, void* d_ws, size_t ws_size,
                              hipStream_t stream) {
    const float* p1 = (const float*)d_in[0];
    const float* p2 = (const float*)d_in[1];
    float* out = (float*)d_out;

    size_t off = 0;
    float4* w       = (float4*)d_ws;               off += (size_t)NB * NPTS * 16;
    int*    hist    = (int*)((char*)d_ws + off);   off += (size_t)NB * NC * 4;
    int*    starts  = (int*)((char*)d_ws + off);   off += (size_t)NB * (NC + 1) * 4 + 8;
    int*    cellof  = (int*)((char*)d_ws + off);   off += (size_t)NB * NPTS * 4;
    float4* wsorted = (float4*)((char*)d_ws + off); off += (size_t)NB * NPTS * 16;
    float4* p2s     = (float4*)((char*)d_ws + off); off += (size_t)NB * NPTS * 16;
    int*    nfail   = (int*)((char*)d_ws + off);   off += 16;
    int*    worklist= (int*)((char*)d_ws + off);   off += (size_t)NB * NPTS * 4;

    if (ws_size < off) {  // fallback: round-2 brute force
        hipMemsetAsync(out, 0, sizeof(float), stream);
        prep_pack<<<(NB * NPTS + 255) / 256, 256, 0, stream>>>(p1, w);
        knn_lap<<<NB * (NPTS / QPB), FB_BLOCK, 0, stream>>>(w, p2, out);
        return;
    }

    hipMemsetAsync(hist, 0, (size_t)NB * NC * 4, stream);
    pack_bin<<<(NB * NPTS + 255) / 256, 256, 0, stream>>>(p1, w, hist, cellof,
                                                          out, nfail);
    scan_cells<<<NB, 1024, 0, stream>>>(hist, starts);
    scatter_all<<<(NB * NPTS + 255) / 256, 256, 0, stream>>>(cellof, starts, hist,
                                                             w, p2, wsorted, p2s);
    phase1<<<NB * (NPTS / QPB), BLOCK, 0, stream>>>(wsorted, p2s, starts, out,
                                                    nfail, worklist);
    phase2<<<P2GRID, P2BLK, 0, stream>>>(wsorted, p2s, nfail, worklist, out);
}

// Round 3
// 121.534 us; speedup vs baseline: 1.0520x; 1.0520x over previous
//
#include <hip/hip_runtime.h>
#include <math.h>

// PointLaplacianLoss — grid-pruned exact KNN, round 13.
//
// Round-12 bug: P1BLOCK was P1Q*WPB/2 = 256, but the geometry needs one
// thread per (query, slice) pair = 32*16 = 512.  Slices 8..15 were never
// computed; the merge read uninitialized LDS -> absmax 1.4.  Fixed:
// P1BLOCK = 512.  Design otherwise identical to round 12:
//   * P1Q=32 queries/block, 8 waves, 16 half-wave slices -> 512 blocks =
//     2 blocks/CU (load-imbalance slack; r11 had 1 block/CU and 20% occ).
//   * batch in bit0 of blockIdx: pair (2g, 2g+1) same spatial group,
//     different batch — evens per-CU work sums.
//   * per-lane sCov (r10-verified), CH=5 prime batching, 20 KB LDS merge.

constexpr int NPTS  = 8192;
constexpr int NB    = 2;
constexpr int KNN   = 10;
constexpr int QPB   = 64;               // fallback kernel's queries/block
constexpr int WPB   = 16;               // phase1 slices per query (stride)
constexpr int P1Q     = 32;             // phase1 queries per block
constexpr int P1BLOCK = P1Q * WPB;      // 512 threads: one per (query,slice)
constexpr int MASK13 = 0xFFFFE000;

constexpr int   G    = 32;
constexpr int   NC   = G * G * G;
constexpr float BMIN = -5.5f;
constexpr float BW   = 11.0f;
constexpr float H    = BW / G;          // 0.34375
constexpr float INVH = (float)G / BW;

// ---------------- selection helpers ----------------
__device__ __forceinline__ void ins1(int l[KNN], int x) {
#pragma unroll
    for (int k = KNN - 1; k > 0; --k) l[k] = min(l[k], max(l[k - 1], x));
    l[0] = min(l[0], x);
}
__device__ __forceinline__ void ins2(int l[KNN], int a, int b) {
    const int b0 = min(a, b), b1 = max(a, b);
#pragma unroll
    for (int k = KNN - 1; k >= 2; --k)
        l[k] = min(l[k], min(max(l[k - 1], b0), max(l[k - 2], b1)));
    l[1] = min(l[1], min(max(l[0], b0), b1));
    l[0] = min(l[0], b0);
}
template<int S>
__device__ __forceinline__ void ins2s(int l[KNN], int a, int b) {
    const int b0 = min(a, b), b1 = max(a, b);
#pragma unroll
    for (int k = KNN - 1; k >= S + 2; --k)
        l[k] = min(l[k], min(max(l[k - 1], b0), max(l[k - 2], b1)));
    l[S + 1] = min(l[S + 1], min(max(l[S], b0), b1));
    l[S] = min(l[S], b0);
}
__device__ __forceinline__ void merge_sorted(int l[KNN], const int p[KNN]) {
    ins2s<0>(l, p[0], p[1]);
    ins2s<2>(l, p[2], p[3]);
    ins2s<4>(l, p[4], p[5]);
    ins2s<6>(l, p[6], p[7]);
    ins2s<8>(l, p[8], p[9]);
}

// ---------------- build kernels ----------------
__global__ void pack_bin(const float* __restrict__ p1, float4* __restrict__ w,
                         int* __restrict__ hist, int* __restrict__ cellof,
                         float* __restrict__ out, int* __restrict__ nfail) {
    const int i = blockIdx.x * blockDim.x + threadIdx.x;
    if (i >= NB * NPTS) return;
    if (i == 0) { out[0] = 0.0f; nfail[0] = 0; }
    const float x = p1[3 * i], y = p1[3 * i + 1], z = p1[3 * i + 2];
    w[i] = make_float4(x, y, z, fmaf(x, x, fmaf(y, y, z * z)));
    const int cx = min(max((int)floorf((x - BMIN) * INVH), 0), G - 1);
    const int cy = min(max((int)floorf((y - BMIN) * INVH), 0), G - 1);
    const int cz = min(max((int)floorf((z - BMIN) * INVH), 0), G - 1);
    const int c = (cz << 10) | (cy << 5) | cx;
    cellof[i] = c;
    atomicAdd(&hist[(i >> 13) * NC + c], 1);
}

__global__ __launch_bounds__(1024)
void scan_cells(const int* __restrict__ hist, int* __restrict__ starts) {
    __shared__ int wsum[16];
    const int b = blockIdx.x, t = threadIdx.x;
    const int* hb = hist + b * NC;
    int* sb = starts + b * (NC + 1);
    const int c0 = t * 32;
    const int4* hb4 = (const int4*)(hb + c0);   // hist 16B-aligned
    int loc[32]; int sum = 0;
#pragma unroll
    for (int j = 0; j < 8; ++j) {
        const int4 v = hb4[j];
        loc[4 * j + 0] = v.x; loc[4 * j + 1] = v.y;
        loc[4 * j + 2] = v.z; loc[4 * j + 3] = v.w;
        sum += v.x + v.y + v.z + v.w;
    }
    const int lane = t & 63, wvi = t >> 6;
    int incl = sum;
#pragma unroll
    for (int off = 1; off < 64; off <<= 1) {
        const int v = __shfl_up(incl, off);
        if (lane >= off) incl += v;
    }
    if (lane == 63) wsum[wvi] = incl;
    __syncthreads();
    if (t < 16) {
        const int v = wsum[t];
        int iv = v;
#pragma unroll
        for (int off = 1; off < 16; off <<= 1) {
            const int u = __shfl_up(iv, off);
            if (t >= off) iv += u;
        }
        wsum[t] = iv - v;
    }
    __syncthreads();
    int run = wsum[wvi] + incl - sum;
#pragma unroll
    for (int j = 0; j < 32; ++j) { sb[c0 + j] = run; run += loc[j]; }
    if (t == 1023) sb[NC] = run;
}

__global__ void scatter_all(const int* __restrict__ cellof,
                            const int* __restrict__ starts,
                            int* __restrict__ hist,
                            const float4* __restrict__ w,
                            const float* __restrict__ p2,
                            float4* __restrict__ wsorted,
                            float4* __restrict__ p2s) {
    const int i = blockIdx.x * blockDim.x + threadIdx.x;
    if (i >= NB * NPTS) return;
    const int b = i >> 13;
    const int c = cellof[i];
    const int old = atomicSub(&hist[b * NC + c], 1);
    const int pos = b * NPTS + starts[b * (NC + 1) + c] + old - 1;
    wsorted[pos] = w[i];
    p2s[pos] = make_float4(p2[3 * i], p2[3 * i + 1], p2[3 * i + 2], 0.0f);
}

// ---------------- phase 1: prime-batched adaptive scan ----------------
// Bounds loaded up-front AND the first candidate of every run prime-loaded in
// predicated chunks of CH=5 independent loads.  `sl` = this lane's slice
// index (0..WPB-1); candidates j == sl (mod WPB).
template<int S>
__device__ __forceinline__ void scan_batched(const float4* __restrict__ W,
                                             const int* __restrict__ st,
                                             int cx, int cy, int cz,
                                             float m2x, float m2y, float m2z,
                                             float q2, int qpos, int sl,
                                             int l[KNN])
{
    constexpr int Wd = 2 * S + 1;
    constexpr int R  = Wd * Wd;
    constexpr int CH = 5;               // prime-chunk width
    const int IMAX = 0x7FFFFFFF;
    int J0[R], J1[R];
#pragma unroll
    for (int r = 0; r < R; ++r) {
        const int dy = r % Wd - S, dz = r / Wd - S;   // compile-time
        const int ay = cy + dy, az = cz + dz;
        const bool ok = ((unsigned)ay < G) && ((unsigned)az < G);
        const int cbase = (az << 10) | (ay << 5);
        const int lo = cbase + max(cx - S, 0);
        const int hi = cbase + min(cx + S, G - 1) + 1;
        J0[r] = ok ? st[lo] : 0;                      // predicated, independent
        J1[r] = ok ? st[hi] : 0;
    }
#pragma unroll
    for (int base = 0; base < R; base += CH) {
        float4 P[CH];
#pragma unroll
        for (int c = 0; c < CH; ++c) {
            const int r = base + c;                   // compile-time
            if (r < R) {
                const int j = min(J0[r] + sl, NPTS - 1);  // clamped, harmless
                P[c] = W[j];
            }
        }
#pragma unroll
        for (int c = 0; c < CH; ++c) {
            const int r = base + c;
            if (r < R) {
                const int j1 = J1[r];
                int j = J0[r] + sl;
                if (j < j1) {
                    float4 c4 = P[c];                 // primed, in flight
                    while (true) {
                        const int jn = j + WPB;
                        const bool more = jn < j1;
                        float4 nx;
                        if (more) nx = W[jn];         // prefetch next
                        const float d2 = fmaf(m2x, c4.x,
                                         fmaf(m2y, c4.y,
                                         fmaf(m2z, c4.z, c4.w + q2)));
                        int key = (__float_as_int(d2) & MASK13) | j;
                        key = (j == qpos) ? IMAX : key;
                        ins1(l, key);
                        if (!more) break;
                        c4 = nx; j = jn;
                    }
                }
            }
        }
    }
}

__global__ __launch_bounds__(P1BLOCK)
void phase1(const float4* __restrict__ wsorted, const float4* __restrict__ p2s,
            const int* __restrict__ starts, float* __restrict__ out,
            int* __restrict__ nfail, int* __restrict__ worklist)
{
    __shared__ int mv[WPB * KNN * P1Q];      // 20 KB

    // batch in bit0: pair (2g, 2g+1) = same spatial group, different batch.
    const int bid   = blockIdx.x;
    const int batch = bid & 1;
    const int g     = bid >> 1;              // 0..255 spatial group
    const int tid   = threadIdx.x;
    const int lane  = tid & 63;
    const int qi    = lane & 31;
    const int slice = ((tid >> 6) << 1) | (lane >> 5);   // 0..15 (8 waves)
    const int qpos  = (g << 5) + qi;

    const float4* W  = wsorted + batch * NPTS;
    const float4* P2 = p2s + batch * NPTS;
    const int*    st = starts + batch * (NC + 1);

    const float4 qp = W[qpos];
    const int cx = min(max((int)floorf((qp.x - BMIN) * INVH), 0), G - 1);
    const int cy = min(max((int)floorf((qp.y - BMIN) * INVH), 0), G - 1);
    const int cz = min(max((int)floorf((qp.z - BMIN) * INVH), 0), G - 1);
    const float lox = BMIN + cx * H, loy = BMIN + cy * H, loz = BMIN + cz * H;
    const float df = fminf(fminf(fminf(qp.x - lox, lox + H - qp.x),
                                 fminf(qp.y - loy, loy + H - qp.y)),
                           fminf(qp.z - loz, loz + H - qp.z));
    const float m2x = -2.0f * qp.x, m2y = -2.0f * qp.y, m2z = -2.0f * qp.z;
    const float q2 = qp.w;
    const int IMAX = 0x7FFFFFFF;

    // per-lane reach (exec-masked): only truly-sparse lanes pay 5^3
    const int sCov = (q2 > 4.8f) ? 2 : 1;

    int l[KNN];
#pragma unroll
    for (int k = 0; k < KNN; ++k) l[k] = IMAX;

    if (sCov == 1)
        scan_batched<1>(W, st, cx, cy, cz, m2x, m2y, m2z, q2, qpos, slice, l);
    else
        scan_batched<2>(W, st, cx, cy, cz, m2x, m2y, m2z, q2, qpos, slice, l);

#pragma unroll
    for (int k = 0; k < KNN; ++k) mv[(slice * KNN + k) * P1Q + qi] = l[k];
    __syncthreads();

    float v = 0.0f;
    if (tid < P1Q) {
        int M[KNN];
#pragma unroll
        for (int k = 0; k < KNN; ++k) M[k] = IMAX;
#pragma unroll
        for (int e = 0; e < WPB; ++e) {
            int p[KNN];
#pragma unroll
            for (int k = 0; k < KNN; ++k) p[k] = mv[(e * KNN + k) * P1Q + tid];
            merge_sorted(M, p);
        }

        const float tau = __int_as_float(M[KNN - 1] & MASK13);
        const float R = (float)sCov * H + df;         // per-lane coverage
        const bool covered = (tau <= R * R * 0.996f); // truncation margin
        if (covered) {
            float s1x = 0, s1y = 0, s1z = 0, s2x = 0, s2y = 0, s2z = 0;
#pragma unroll
            for (int k = 0; k < KNN; ++k) {
                const int j = M[k] & (NPTS - 1);
                const float4 c4 = W[j];
                const float4 n2 = P2[j];
                s1x += c4.x; s1y += c4.y; s1z += c4.z;
                s2x += n2.x; s2y += n2.y; s2z += n2.z;
            }
            const float4 p2v = P2[qpos];
            const float dx = (s1x * 0.1f - qp.x) - (s2x * 0.1f - p2v.x);
            const float dy2 = (s1y * 0.1f - qp.y) - (s2y * 0.1f - p2v.y);
            const float dz2 = (s1z * 0.1f - qp.z) - (s2z * 0.1f - p2v.z);
            v = fabsf(dx) + fabsf(dy2) + fabsf(dz2);
        } else {
            const int wi = atomicAdd(nfail, 1);
            worklist[wi] = (batch << 16) | qpos;
        }
    }
    if (tid < 64) {   // whole first wave -> shuffles well-defined
#pragma unroll
        for (int off = 32; off >= 1; off >>= 1) v += __shfl_down(v, off);
        if (tid == 0)
            atomicAdd(out, v * (1.0f / (float)(NB * NPTS * 3)));
    }
}

// ---------------- phase 2: wave-per-query exact brute force ----------------
constexpr int P2BLK = 256;
constexpr int P2GRID = 512;

__global__ __launch_bounds__(P2BLK)
void phase2(const float4* __restrict__ wsorted, const float4* __restrict__ p2s,
            const int* __restrict__ nfail, const int* __restrict__ worklist,
            float* __restrict__ out)
{
    const int lane = threadIdx.x & 63;
    const int wv   = threadIdx.x >> 6;
    const int wid  = blockIdx.x * (P2BLK / 64) + wv;
    const int NW   = P2GRID * (P2BLK / 64);
    const int nf   = *nfail;
    const int IMAX = 0x7FFFFFFF;
    float acc = 0.0f;

    for (int i = wid; i < nf; i += NW) {
        const int e = worklist[i];
        const int batch = e >> 16, qpos = e & 0xFFFF;
        const float4* W  = wsorted + batch * NPTS;
        const float4* P2 = p2s + batch * NPTS;
        const float4 qp = W[qpos];
        const float m2x = -2.0f * qp.x, m2y = -2.0f * qp.y, m2z = -2.0f * qp.z;
        const float q2 = qp.w;

        int l[KNN];
#pragma unroll
        for (int k = 0; k < KNN; ++k) l[k] = IMAX;

#pragma unroll 2
        for (int it = 0; it < NPTS / 128; ++it) {
            const int ja = it * 128 + lane, jb = ja + 64;
            const float4 ca = W[ja];
            const float4 cb = W[jb];
            const float da = fmaf(m2x, ca.x, fmaf(m2y, ca.y, fmaf(m2z, ca.z, ca.w + q2)));
            const float db = fmaf(m2x, cb.x, fmaf(m2y, cb.y, fmaf(m2z, cb.z, cb.w + q2)));
            int ka = (__float_as_int(da) & MASK13) | ja;
            int kb = (__float_as_int(db) & MASK13) | jb;
            ka = (ja == qpos) ? IMAX : ka;
            kb = (jb == qpos) ? IMAX : kb;
            ins2(l, ka, kb);
        }
        for (int off = 1; off < 64; off <<= 1) {
            int p[KNN];
#pragma unroll
            for (int k = 0; k < KNN; ++k) p[k] = __shfl_xor(l[k], off);
            merge_sorted(l, p);
        }
        float s1x = 0, s1y = 0, s1z = 0, s2x = 0, s2y = 0, s2z = 0;
#pragma unroll
        for (int k = 0; k < KNN; ++k) {
            const int j = l[k] & (NPTS - 1);
            const float4 c4 = W[j];
            const float4 n2 = P2[j];
            s1x += c4.x; s1y += c4.y; s1z += c4.z;
            s2x += n2.x; s2y += n2.y; s2z += n2.z;
        }
        const float4 p2v = P2[qpos];
        const float dx = (s1x * 0.1f - qp.x) - (s2x * 0.1f - p2v.x);
        const float dy = (s1y * 0.1f - qp.y) - (s2y * 0.1f - p2v.y);
        const float dz = (s1z * 0.1f - qp.z) - (s2z * 0.1f - p2v.z);
        if (lane == 0) acc += fabsf(dx) + fabsf(dy) + fabsf(dz);
    }

    if (lane == 0 && acc != 0.0f)
        atomicAdd(out, acc * (1.0f / (float)(NB * NPTS * 3)));
}

// ---------------- round-2 fallback (O(N^2), verified) ----------------
constexpr int FB_WPB = 8;
constexpr int FB_BLOCK = QPB * FB_WPB;  // 512
constexpr int CHUNK = NPTS / FB_WPB;

__global__ void prep_pack(const float* __restrict__ p, float4* __restrict__ w) {
    const int i = blockIdx.x * blockDim.x + threadIdx.x;
    if (i < NB * NPTS) {
        const float x = p[3 * i], y = p[3 * i + 1], z = p[3 * i + 2];
        w[i] = make_float4(x, y, z, fmaf(x, x, fmaf(y, y, z * z)));
    }
}

__global__ __launch_bounds__(FB_BLOCK, 2)
void knn_lap(const float4* __restrict__ w1, const float* __restrict__ p2,
             float* __restrict__ out)
{
    __shared__ int mv[FB_WPB * KNN * QPB];
    const int batch = blockIdx.x >> 7;
    const int qbase = (blockIdx.x & 127) << 6;
    const int lane  = threadIdx.x & 63;
    const int wv    = __builtin_amdgcn_readfirstlane(threadIdx.x >> 6);
    const int query = qbase + lane;
    const float4* Wb = w1 + batch * NPTS;
    const float4 qp = Wb[query];
    const float m2x = -2.0f * qp.x, m2y = -2.0f * qp.y, m2z = -2.0f * qp.z;
    const float q2 = qp.w;
    const int IMAX = 0x7FFFFFFF;
    int l[KNN];
#pragma unroll
    for (int k = 0; k < KNN; ++k) l[k] = IMAX;
    const int c0 = wv * CHUNK;
    const float4* cand = Wb + c0;
#pragma unroll 4
    for (int i = 0; i < CHUNK; i += 2) {
        const float4 ca = cand[i];
        const float4 cb = cand[i + 1];
        const int ja = c0 + i, jb = ja + 1;
        const float da = fmaf(m2x, ca.x, fmaf(m2y, ca.y, fmaf(m2z, ca.z, ca.w + q2)));
        const float db = fmaf(m2x, cb.x, fmaf(m2y, cb.y, fmaf(m2z, cb.z, cb.w + q2)));
        int ka = (__float_as_int(da) & MASK13) | ja;
        int kb = (__float_as_int(db) & MASK13) | jb;
        ka = (ja == query) ? IMAX : ka;
        kb = (jb == query) ? IMAX : kb;
        ins2(l, ka, kb);
    }
#pragma unroll
    for (int k = 0; k < KNN; ++k) mv[(wv * KNN + k) * QPB + lane] = l[k];
    __syncthreads();
    if (threadIdx.x < QPB) {
        int m[KNN];
#pragma unroll
        for (int k = 0; k < KNN; ++k) m[k] = IMAX;
#pragma unroll
        for (int e = 0; e < FB_WPB; ++e) {
            int p[KNN];
#pragma unroll
            for (int k = 0; k < KNN; ++k) p[k] = mv[(e * KNN + k) * QPB + lane];
            merge_sorted(m, p);
        }
        const float* P2b = p2 + (size_t)batch * NPTS * 3;
        float s1x = 0, s1y = 0, s1z = 0, s2x = 0, s2y = 0, s2z = 0;
#pragma unroll
        for (int k = 0; k < KNN; ++k) {
            const int j = m[k] & (NPTS - 1);
            const float4 c = Wb[j];
            s1x += c.x; s1y += c.y; s1z += c.z;
            s2x += P2b[3 * j + 0]; s2y += P2b[3 * j + 1]; s2z += P2b[3 * j + 2];
        }
        const int q = qbase + threadIdx.x;
        const float p2x = P2b[3 * q + 0], p2y = P2b[3 * q + 1], p2z = P2b[3 * q + 2];
        const float dx = (s1x * 0.1f - qp.x) - (s2x * 0.1f - p2x);
        const float dy = (s1y * 0.1f - qp.y) - (s2y * 0.1f - p2y);
        const float dz = (s1z * 0.1f - qp.z) - (s2z * 0.1f - p2z);
        float v = fabsf(dx) + fabsf(dy) + fabsf(dz);
#pragma unroll
        for (int off = 32; off >= 1; off >>= 1) v += __shfl_down(v, off);
        if (threadIdx.x == 0)
            atomicAdd(out, v * (1.0f / (float)(NB * NPTS * 3)));
    }
}

// ---------------- launcher ----------------
extern "C" void kernel_launch(void* const* d_in, const int* in_sizes, int n_in,
                              void* d_out, int out_size, void* d_ws, size_t ws_size,
                              hipStream_t stream) {
    const float* p1 = (const float*)d_in[0];
    const float* p2 = (const float*)d_in[1];
    float* out = (float*)d_out;

    size_t off = 0;
    float4* w       = (float4*)d_ws;               off += (size_t)NB * NPTS * 16;
    int*    hist    = (int*)((char*)d_ws + off);   off += (size_t)NB * NC * 4;
    int*    starts  = (int*)((char*)d_ws + off);   off += (size_t)NB * (NC + 1) * 4 + 8;
    int*    cellof  = (int*)((char*)d_ws + off);   off += (size_t)NB * NPTS * 4;
    float4* wsorted = (float4*)((char*)d_ws + off); off += (size_t)NB * NPTS * 16;
    float4* p2s     = (float4*)((char*)d_ws + off); off += (size_t)NB * NPTS * 16;
    int*    nfail   = (int*)((char*)d_ws + off);   off += 16;
    int*    worklist= (int*)((char*)d_ws + off);   off += (size_t)NB * NPTS * 4;

    if (ws_size < off) {  // fallback: round-2 brute force
        hipMemsetAsync(out, 0, sizeof(float), stream);
        prep_pack<<<(NB * NPTS + 255) / 256, 256, 0, stream>>>(p1, w);
        knn_lap<<<NB * (NPTS / QPB), FB_BLOCK, 0, stream>>>(w, p2, out);
        return;
    }

    hipMemsetAsync(hist, 0, (size_t)NB * NC * 4, stream);
    pack_bin<<<(NB * NPTS + 255) / 256, 256, 0, stream>>>(p1, w, hist, cellof,
                                                          out, nfail);
    scan_cells<<<NB, 1024, 0, stream>>>(hist, starts);
    scatter_all<<<(NB * NPTS + 255) / 256, 256, 0, stream>>>(cellof, starts, hist,
                                                             w, p2, wsorted, p2s);
    phase1<<<NB * (NPTS / P1Q), P1BLOCK, 0, stream>>>(wsorted, p2s, starts, out,
                                                      nfail, worklist);
    phase2<<<P2GRID, P2BLK, 0, stream>>>(wsorted, p2s, nfail, worklist, out);
}

// Round 4
// 116.284 us; speedup vs baseline: 1.0995x; 1.0452x over previous
//
#include <hip/hip_runtime.h>
#include <math.h>

// PointLaplacianLoss — grid-pruned exact KNN, round 14.
//
// Round-13 post-mortem: phase1 ~34us vs a ~1.6us VALU floor — it is bound by
// memory TRANSACTIONS, not compute.  Old lane map put 32 different queries in
// lanes 0..31, so every gather wave-load touched up to 64 cache lines.
// This round transposes the mapping:
//   * qi = tid>>4, sl = tid&15 — a 16-lane group owns all 16 slices of ONE
//     query.  Gather loads are J0[r]+0..15 = 16 consecutive float4 = 256 B
//     contiguous -> 16 lines/wave (4x fewer); bounds loads become
//     group-broadcast (4 distinct addrs/wave instead of 64).
//   * mv LDS re-laid out [qi][slice][k] with stride WPB*KNN+1=161 ints:
//     writes <=2-way bank aliasing (free), merge reads conflict-free.
//   * Same candidate partition per query — bitwise-identical result.
// Everything else (per-lane sCov, CH=5 prime batching, 2 blocks/CU,
// batch-in-bit0, build pipeline, phase2) unchanged from round 13.

constexpr int NPTS  = 8192;
constexpr int NB    = 2;
constexpr int KNN   = 10;
constexpr int QPB   = 64;               // fallback kernel's queries/block
constexpr int WPB   = 16;               // phase1 slices per query (stride)
constexpr int P1Q     = 32;             // phase1 queries per block
constexpr int P1BLOCK = P1Q * WPB;      // 512 threads: one per (query,slice)
constexpr int MVSTR   = WPB * KNN + 1;  // 161: padded per-query LDS stride
constexpr int MASK13 = 0xFFFFE000;

constexpr int   G    = 32;
constexpr int   NC   = G * G * G;
constexpr float BMIN = -5.5f;
constexpr float BW   = 11.0f;
constexpr float H    = BW / G;          // 0.34375
constexpr float INVH = (float)G / BW;

// ---------------- selection helpers ----------------
__device__ __forceinline__ void ins1(int l[KNN], int x) {
#pragma unroll
    for (int k = KNN - 1; k > 0; --k) l[k] = min(l[k], max(l[k - 1], x));
    l[0] = min(l[0], x);
}
__device__ __forceinline__ void ins2(int l[KNN], int a, int b) {
    const int b0 = min(a, b), b1 = max(a, b);
#pragma unroll
    for (int k = KNN - 1; k >= 2; --k)
        l[k] = min(l[k], min(max(l[k - 1], b0), max(l[k - 2], b1)));
    l[1] = min(l[1], min(max(l[0], b0), b1));
    l[0] = min(l[0], b0);
}
template<int S>
__device__ __forceinline__ void ins2s(int l[KNN], int a, int b) {
    const int b0 = min(a, b), b1 = max(a, b);
#pragma unroll
    for (int k = KNN - 1; k >= S + 2; --k)
        l[k] = min(l[k], min(max(l[k - 1], b0), max(l[k - 2], b1)));
    l[S + 1] = min(l[S + 1], min(max(l[S], b0), b1));
    l[S] = min(l[S], b0);
}
__device__ __forceinline__ void merge_sorted(int l[KNN], const int p[KNN]) {
    ins2s<0>(l, p[0], p[1]);
    ins2s<2>(l, p[2], p[3]);
    ins2s<4>(l, p[4], p[5]);
    ins2s<6>(l, p[6], p[7]);
    ins2s<8>(l, p[8], p[9]);
}

// ---------------- build kernels ----------------
__global__ void pack_bin(const float* __restrict__ p1, float4* __restrict__ w,
                         int* __restrict__ hist, int* __restrict__ cellof,
                         float* __restrict__ out, int* __restrict__ nfail) {
    const int i = blockIdx.x * blockDim.x + threadIdx.x;
    if (i >= NB * NPTS) return;
    if (i == 0) { out[0] = 0.0f; nfail[0] = 0; }
    const float x = p1[3 * i], y = p1[3 * i + 1], z = p1[3 * i + 2];
    w[i] = make_float4(x, y, z, fmaf(x, x, fmaf(y, y, z * z)));
    const int cx = min(max((int)floorf((x - BMIN) * INVH), 0), G - 1);
    const int cy = min(max((int)floorf((y - BMIN) * INVH), 0), G - 1);
    const int cz = min(max((int)floorf((z - BMIN) * INVH), 0), G - 1);
    const int c = (cz << 10) | (cy << 5) | cx;
    cellof[i] = c;
    atomicAdd(&hist[(i >> 13) * NC + c], 1);
}

__global__ __launch_bounds__(1024)
void scan_cells(const int* __restrict__ hist, int* __restrict__ starts) {
    __shared__ int wsum[16];
    const int b = blockIdx.x, t = threadIdx.x;
    const int* hb = hist + b * NC;
    int* sb = starts + b * (NC + 1);
    const int c0 = t * 32;
    const int4* hb4 = (const int4*)(hb + c0);   // hist 16B-aligned
    int loc[32]; int sum = 0;
#pragma unroll
    for (int j = 0; j < 8; ++j) {
        const int4 v = hb4[j];
        loc[4 * j + 0] = v.x; loc[4 * j + 1] = v.y;
        loc[4 * j + 2] = v.z; loc[4 * j + 3] = v.w;
        sum += v.x + v.y + v.z + v.w;
    }
    const int lane = t & 63, wvi = t >> 6;
    int incl = sum;
#pragma unroll
    for (int off = 1; off < 64; off <<= 1) {
        const int v = __shfl_up(incl, off);
        if (lane >= off) incl += v;
    }
    if (lane == 63) wsum[wvi] = incl;
    __syncthreads();
    if (t < 16) {
        const int v = wsum[t];
        int iv = v;
#pragma unroll
        for (int off = 1; off < 16; off <<= 1) {
            const int u = __shfl_up(iv, off);
            if (t >= off) iv += u;
        }
        wsum[t] = iv - v;
    }
    __syncthreads();
    int run = wsum[wvi] + incl - sum;
#pragma unroll
    for (int j = 0; j < 32; ++j) { sb[c0 + j] = run; run += loc[j]; }
    if (t == 1023) sb[NC] = run;
}

__global__ void scatter_all(const int* __restrict__ cellof,
                            const int* __restrict__ starts,
                            int* __restrict__ hist,
                            const float4* __restrict__ w,
                            const float* __restrict__ p2,
                            float4* __restrict__ wsorted,
                            float4* __restrict__ p2s) {
    const int i = blockIdx.x * blockDim.x + threadIdx.x;
    if (i >= NB * NPTS) return;
    const int b = i >> 13;
    const int c = cellof[i];
    const int old = atomicSub(&hist[b * NC + c], 1);
    const int pos = b * NPTS + starts[b * (NC + 1) + c] + old - 1;
    wsorted[pos] = w[i];
    p2s[pos] = make_float4(p2[3 * i], p2[3 * i + 1], p2[3 * i + 2], 0.0f);
}

// ---------------- phase 1: prime-batched adaptive scan ----------------
// Bounds loaded up-front AND the first candidate of every run prime-loaded in
// predicated chunks of CH=5 independent loads.  `sl` = this lane's slice
// index (0..WPB-1); candidates j == sl (mod WPB).  With the transposed lane
// map (16 lanes = 16 slices of one query), these loads are contiguous.
template<int S>
__device__ __forceinline__ void scan_batched(const float4* __restrict__ W,
                                             const int* __restrict__ st,
                                             int cx, int cy, int cz,
                                             float m2x, float m2y, float m2z,
                                             float q2, int qpos, int sl,
                                             int l[KNN])
{
    constexpr int Wd = 2 * S + 1;
    constexpr int R  = Wd * Wd;
    constexpr int CH = 5;               // prime-chunk width
    const int IMAX = 0x7FFFFFFF;
    int J0[R], J1[R];
#pragma unroll
    for (int r = 0; r < R; ++r) {
        const int dy = r % Wd - S, dz = r / Wd - S;   // compile-time
        const int ay = cy + dy, az = cz + dz;
        const bool ok = ((unsigned)ay < G) && ((unsigned)az < G);
        const int cbase = (az << 10) | (ay << 5);
        const int lo = cbase + max(cx - S, 0);
        const int hi = cbase + min(cx + S, G - 1) + 1;
        J0[r] = ok ? st[lo] : 0;                      // group-broadcast loads
        J1[r] = ok ? st[hi] : 0;
    }
#pragma unroll
    for (int base = 0; base < R; base += CH) {
        float4 P[CH];
#pragma unroll
        for (int c = 0; c < CH; ++c) {
            const int r = base + c;                   // compile-time
            if (r < R) {
                const int j = min(J0[r] + sl, NPTS - 1);  // clamped, harmless
                P[c] = W[j];                          // 16 consecutive float4
            }
        }
#pragma unroll
        for (int c = 0; c < CH; ++c) {
            const int r = base + c;
            if (r < R) {
                const int j1 = J1[r];
                int j = J0[r] + sl;
                if (j < j1) {
                    float4 c4 = P[c];                 // primed, in flight
                    while (true) {
                        const int jn = j + WPB;
                        const bool more = jn < j1;
                        float4 nx;
                        if (more) nx = W[jn];         // prefetch next (contig)
                        const float d2 = fmaf(m2x, c4.x,
                                         fmaf(m2y, c4.y,
                                         fmaf(m2z, c4.z, c4.w + q2)));
                        int key = (__float_as_int(d2) & MASK13) | j;
                        key = (j == qpos) ? IMAX : key;
                        ins1(l, key);
                        if (!more) break;
                        c4 = nx; j = jn;
                    }
                }
            }
        }
    }
}

__global__ __launch_bounds__(P1BLOCK)
void phase1(const float4* __restrict__ wsorted, const float4* __restrict__ p2s,
            const int* __restrict__ starts, float* __restrict__ out,
            int* __restrict__ nfail, int* __restrict__ worklist)
{
    __shared__ int mv[P1Q * MVSTR];          // 32*161*4 = 20.6 KB

    // batch in bit0: pair (2g, 2g+1) = same spatial group, different batch.
    const int bid   = blockIdx.x;
    const int batch = bid & 1;
    const int g     = bid >> 1;              // 0..255 spatial group
    const int tid   = threadIdx.x;
    // TRANSPOSED map: a 16-lane group owns all 16 slices of one query.
    const int qi    = tid >> 4;              // 0..31 query within block
    const int sl    = tid & 15;              // 0..15 slice
    const int qpos  = (g << 5) + qi;

    const float4* W  = wsorted + batch * NPTS;
    const float4* P2 = p2s + batch * NPTS;
    const int*    st = starts + batch * (NC + 1);

    const float4 qp = W[qpos];
    const int cx = min(max((int)floorf((qp.x - BMIN) * INVH), 0), G - 1);
    const int cy = min(max((int)floorf((qp.y - BMIN) * INVH), 0), G - 1);
    const int cz = min(max((int)floorf((qp.z - BMIN) * INVH), 0), G - 1);
    const float lox = BMIN + cx * H, loy = BMIN + cy * H, loz = BMIN + cz * H;
    const float df = fminf(fminf(fminf(qp.x - lox, lox + H - qp.x),
                                 fminf(qp.y - loy, loy + H - qp.y)),
                           fminf(qp.z - loz, loz + H - qp.z));
    const float m2x = -2.0f * qp.x, m2y = -2.0f * qp.y, m2z = -2.0f * qp.z;
    const float q2 = qp.w;
    const int IMAX = 0x7FFFFFFF;

    // per-query reach (uniform across the 16-lane group): only truly-sparse
    // queries pay 5^3.
    const int sCov = (q2 > 4.8f) ? 2 : 1;

    int l[KNN];
#pragma unroll
    for (int k = 0; k < KNN; ++k) l[k] = IMAX;

    if (sCov == 1)
        scan_batched<1>(W, st, cx, cy, cz, m2x, m2y, m2z, q2, qpos, sl, l);
    else
        scan_batched<2>(W, st, cx, cy, cz, m2x, m2y, m2z, q2, qpos, sl, l);

#pragma unroll
    for (int k = 0; k < KNN; ++k) mv[qi * MVSTR + sl * KNN + k] = l[k];
    __syncthreads();

    float v = 0.0f;
    if (tid < P1Q) {
        int M[KNN];
#pragma unroll
        for (int k = 0; k < KNN; ++k) M[k] = IMAX;
#pragma unroll
        for (int e = 0; e < WPB; ++e) {
            int p[KNN];
#pragma unroll
            for (int k = 0; k < KNN; ++k) p[k] = mv[tid * MVSTR + e * KNN + k];
            merge_sorted(M, p);
        }

        const float tau = __int_as_float(M[KNN - 1] & MASK13);
        // recompute this query's sCov (tid-th query of the block)
        const float4 qq = W[(g << 5) + tid];
        const int sc = (qq.w > 4.8f) ? 2 : 1;
        const int qcx = min(max((int)floorf((qq.x - BMIN) * INVH), 0), G - 1);
        const int qcy = min(max((int)floorf((qq.y - BMIN) * INVH), 0), G - 1);
        const int qcz = min(max((int)floorf((qq.z - BMIN) * INVH), 0), G - 1);
        const float qlx = BMIN + qcx * H, qly = BMIN + qcy * H, qlz = BMIN + qcz * H;
        const float qdf = fminf(fminf(fminf(qq.x - qlx, qlx + H - qq.x),
                                      fminf(qq.y - qly, qly + H - qq.y)),
                                fminf(qq.z - qlz, qlz + H - qq.z));
        const float R = (float)sc * H + qdf;          // coverage radius
        const bool covered = (tau <= R * R * 0.996f); // truncation margin
        if (covered) {
            float s1x = 0, s1y = 0, s1z = 0, s2x = 0, s2y = 0, s2z = 0;
#pragma unroll
            for (int k = 0; k < KNN; ++k) {
                const int j = M[k] & (NPTS - 1);
                const float4 c4 = W[j];
                const float4 n2 = P2[j];
                s1x += c4.x; s1y += c4.y; s1z += c4.z;
                s2x += n2.x; s2y += n2.y; s2z += n2.z;
            }
            const float4 p2v = P2[(g << 5) + tid];
            const float dx = (s1x * 0.1f - qq.x) - (s2x * 0.1f - p2v.x);
            const float dy2 = (s1y * 0.1f - qq.y) - (s2y * 0.1f - p2v.y);
            const float dz2 = (s1z * 0.1f - qq.z) - (s2z * 0.1f - p2v.z);
            v = fabsf(dx) + fabsf(dy2) + fabsf(dz2);
        } else {
            const int wi = atomicAdd(nfail, 1);
            worklist[wi] = (batch << 16) | ((g << 5) + tid);
        }
    }
    if (tid < 64) {   // whole first wave -> shuffles well-defined
#pragma unroll
        for (int off = 32; off >= 1; off >>= 1) v += __shfl_down(v, off);
        if (tid == 0)
            atomicAdd(out, v * (1.0f / (float)(NB * NPTS * 3)));
    }
}

// ---------------- phase 2: wave-per-query exact brute force ----------------
constexpr int P2BLK = 256;
constexpr int P2GRID = 512;

__global__ __launch_bounds__(P2BLK)
void phase2(const float4* __restrict__ wsorted, const float4* __restrict__ p2s,
            const int* __restrict__ nfail, const int* __restrict__ worklist,
            float* __restrict__ out)
{
    const int lane = threadIdx.x & 63;
    const int wv   = threadIdx.x >> 6;
    const int wid  = blockIdx.x * (P2BLK / 64) + wv;
    const int NW   = P2GRID * (P2BLK / 64);
    const int nf   = *nfail;
    const int IMAX = 0x7FFFFFFF;
    float acc = 0.0f;

    for (int i = wid; i < nf; i += NW) {
        const int e = worklist[i];
        const int batch = e >> 16, qpos = e & 0xFFFF;
        const float4* W  = wsorted + batch * NPTS;
        const float4* P2 = p2s + batch * NPTS;
        const float4 qp = W[qpos];
        const float m2x = -2.0f * qp.x, m2y = -2.0f * qp.y, m2z = -2.0f * qp.z;
        const float q2 = qp.w;

        int l[KNN];
#pragma unroll
        for (int k = 0; k < KNN; ++k) l[k] = IMAX;

#pragma unroll 2
        for (int it = 0; it < NPTS / 128; ++it) {
            const int ja = it * 128 + lane, jb = ja + 64;
            const float4 ca = W[ja];
            const float4 cb = W[jb];
            const float da = fmaf(m2x, ca.x, fmaf(m2y, ca.y, fmaf(m2z, ca.z, ca.w + q2)));
            const float db = fmaf(m2x, cb.x, fmaf(m2y, cb.y, fmaf(m2z, cb.z, cb.w + q2)));
            int ka = (__float_as_int(da) & MASK13) | ja;
            int kb = (__float_as_int(db) & MASK13) | jb;
            ka = (ja == qpos) ? IMAX : ka;
            kb = (jb == qpos) ? IMAX : kb;
            ins2(l, ka, kb);
        }
        for (int off = 1; off < 64; off <<= 1) {
            int p[KNN];
#pragma unroll
            for (int k = 0; k < KNN; ++k) p[k] = __shfl_xor(l[k], off);
            merge_sorted(l, p);
        }
        float s1x = 0, s1y = 0, s1z = 0, s2x = 0, s2y = 0, s2z = 0;
#pragma unroll
        for (int k = 0; k < KNN; ++k) {
            const int j = l[k] & (NPTS - 1);
            const float4 c4 = W[j];
            const float4 n2 = P2[j];
            s1x += c4.x; s1y += c4.y; s1z += c4.z;
            s2x += n2.x; s2y += n2.y; s2z += n2.z;
        }
        const float4 p2v = P2[qpos];
        const float dx = (s1x * 0.1f - qp.x) - (s2x * 0.1f - p2v.x);
        const float dy = (s1y * 0.1f - qp.y) - (s2y * 0.1f - p2v.y);
        const float dz = (s1z * 0.1f - qp.z) - (s2z * 0.1f - p2v.z);
        if (lane == 0) acc += fabsf(dx) + fabsf(dy) + fabsf(dz);
    }

    if (lane == 0 && acc != 0.0f)
        atomicAdd(out, acc * (1.0f / (float)(NB * NPTS * 3)));
}

// ---------------- round-2 fallback (O(N^2), verified) ----------------
constexpr int FB_WPB = 8;
constexpr int FB_BLOCK = QPB * FB_WPB;  // 512
constexpr int CHUNK = NPTS / FB_WPB;

__global__ void prep_pack(const float* __restrict__ p, float4* __restrict__ w) {
    const int i = blockIdx.x * blockDim.x + threadIdx.x;
    if (i < NB * NPTS) {
        const float x = p[3 * i], y = p[3 * i + 1], z = p[3 * i + 2];
        w[i] = make_float4(x, y, z, fmaf(x, x, fmaf(y, y, z * z)));
    }
}

__global__ __launch_bounds__(FB_BLOCK, 2)
void knn_lap(const float4* __restrict__ w1, const float* __restrict__ p2,
             float* __restrict__ out)
{
    __shared__ int mv[FB_WPB * KNN * QPB];
    const int batch = blockIdx.x >> 7;
    const int qbase = (blockIdx.x & 127) << 6;
    const int lane  = threadIdx.x & 63;
    const int wv    = __builtin_amdgcn_readfirstlane(threadIdx.x >> 6);
    const int query = qbase + lane;
    const float4* Wb = w1 + batch * NPTS;
    const float4 qp = Wb[query];
    const float m2x = -2.0f * qp.x, m2y = -2.0f * qp.y, m2z = -2.0f * qp.z;
    const float q2 = qp.w;
    const int IMAX = 0x7FFFFFFF;
    int l[KNN];
#pragma unroll
    for (int k = 0; k < KNN; ++k) l[k] = IMAX;
    const int c0 = wv * CHUNK;
    const float4* cand = Wb + c0;
#pragma unroll 4
    for (int i = 0; i < CHUNK; i += 2) {
        const float4 ca = cand[i];
        const float4 cb = cand[i + 1];
        const int ja = c0 + i, jb = ja + 1;
        const float da = fmaf(m2x, ca.x, fmaf(m2y, ca.y, fmaf(m2z, ca.z, ca.w + q2)));
        const float db = fmaf(m2x, cb.x, fmaf(m2y, cb.y, fmaf(m2z, cb.z, cb.w + q2)));
        int ka = (__float_as_int(da) & MASK13) | ja;
        int kb = (__float_as_int(db) & MASK13) | jb;
        ka = (ja == query) ? IMAX : ka;
        kb = (jb == query) ? IMAX : kb;
        ins2(l, ka, kb);
    }
#pragma unroll
    for (int k = 0; k < KNN; ++k) mv[(wv * KNN + k) * QPB + lane] = l[k];
    __syncthreads();
    if (threadIdx.x < QPB) {
        int m[KNN];
#pragma unroll
        for (int k = 0; k < KNN; ++k) m[k] = IMAX;
#pragma unroll
        for (int e = 0; e < FB_WPB; ++e) {
            int p[KNN];
#pragma unroll
            for (int k = 0; k < KNN; ++k) p[k] = mv[(e * KNN + k) * QPB + lane];
            merge_sorted(m, p);
        }
        const float* P2b = p2 + (size_t)batch * NPTS * 3;
        float s1x = 0, s1y = 0, s1z = 0, s2x = 0, s2y = 0, s2z = 0;
#pragma unroll
        for (int k = 0; k < KNN; ++k) {
            const int j = m[k] & (NPTS - 1);
            const float4 c = Wb[j];
            s1x += c.x; s1y += c.y; s1z += c.z;
            s2x += P2b[3 * j + 0]; s2y += P2b[3 * j + 1]; s2z += P2b[3 * j + 2];
        }
        const int q = qbase + threadIdx.x;
        const float p2x = P2b[3 * q + 0], p2y = P2b[3 * q + 1], p2z = P2b[3 * q + 2];
        const float dx = (s1x * 0.1f - qp.x) - (s2x * 0.1f - p2x);
        const float dy = (s1y * 0.1f - qp.y) - (s2y * 0.1f - p2y);
        const float dz = (s1z * 0.1f - qp.z) - (s2z * 0.1f - p2z);
        float v = fabsf(dx) + fabsf(dy) + fabsf(dz);
#pragma unroll
        for (int off = 32; off >= 1; off >>= 1) v += __shfl_down(v, off);
        if (threadIdx.x == 0)
            atomicAdd(out, v * (1.0f / (float)(NB * NPTS * 3)));
    }
}

// ---------------- launcher ----------------
extern "C" void kernel_launch(void* const* d_in, const int* in_sizes, int n_in,
                              void* d_out, int out_size, void* d_ws, size_t ws_size,
                              hipStream_t stream) {
    const float* p1 = (const float*)d_in[0];
    const float* p2 = (const float*)d_in[1];
    float* out = (float*)d_out;

    size_t off = 0;
    float4* w       = (float4*)d_ws;               off += (size_t)NB * NPTS * 16;
    int*    hist    = (int*)((char*)d_ws + off);   off += (size_t)NB * NC * 4;
    int*    starts  = (int*)((char*)d_ws + off);   off += (size_t)NB * (NC + 1) * 4 + 8;
    int*    cellof  = (int*)((char*)d_ws + off);   off += (size_t)NB * NPTS * 4;
    float4* wsorted = (float4*)((char*)d_ws + off); off += (size_t)NB * NPTS * 16;
    float4* p2s     = (float4*)((char*)d_ws + off); off += (size_t)NB * NPTS * 16;
    int*    nfail   = (int*)((char*)d_ws + off);   off += 16;
    int*    worklist= (int*)((char*)d_ws + off);   off += (size_t)NB * NPTS * 4;

    if (ws_size < off) {  // fallback: round-2 brute force
        hipMemsetAsync(out, 0, sizeof(float), stream);
        prep_pack<<<(NB * NPTS + 255) / 256, 256, 0, stream>>>(p1, w);
        knn_lap<<<NB * (NPTS / QPB), FB_BLOCK, 0, stream>>>(w, p2, out);
        return;
    }

    hipMemsetAsync(hist, 0, (size_t)NB * NC * 4, stream);
    pack_bin<<<(NB * NPTS + 255) / 256, 256, 0, stream>>>(p1, w, hist, cellof,
                                                          out, nfail);
    scan_cells<<<NB, 1024, 0, stream>>>(hist, starts);
    scatter_all<<<(NB * NPTS + 255) / 256, 256, 0, stream>>>(cellof, starts, hist,
                                                             w, p2, wsorted, p2s);
    phase1<<<NB * (NPTS / P1Q), P1BLOCK, 0, stream>>>(wsorted, p2s, starts, out,
                                                      nfail, worklist);
    phase2<<<P2GRID, P2BLK, 0, stream>>>(wsorted, p2s, nfail, worklist, out);
}